// Round 3
// baseline (386.700 us; speedup 1.0000x reference)
//
#include <hip/hip_runtime.h>
#include <math.h>

// Problem constants (B=2,S=2048,D=768,E=8,F=3072)
#define T_TOK 4096
#define DDIM  768
#define EXP   8
#define FDIM  3072
#define W8CNT ((EXP * FDIM * DDIM) / 8)   // 2359296 8-float units per weight tensor

typedef __bf16 bf16x8 __attribute__((ext_vector_type(8)));
typedef float  f32x4  __attribute__((ext_vector_type(4)));

__device__ __forceinline__ ushort f2bf(float f) {
    union { float f; unsigned u; } v; v.f = f;
    unsigned r = v.u + 0x7fffu + ((v.u >> 16) & 1u);   // RNE
    return (ushort)(r >> 16);
}

// async global->LDS, 16B per lane; LDS base wave-uniform (HW adds lane*16)
__device__ __forceinline__ void gl_lds16(const void* g, void* l) {
    __builtin_amdgcn_global_load_lds(
        (__attribute__((address_space(1))) void*)(g),
        (__attribute__((address_space(3))) void*)(l), 16, 0, 0);
}

__device__ __forceinline__ void convert_body(const float* __restrict__ src,
                                             ushort* __restrict__ dst,
                                             int idx0, int stride) {
    for (int i = idx0; i < W8CNT; i += stride) {
        const float4* s = (const float4*)(src + (size_t)i * 8);
        float4 a = s[0], b = s[1];
        uint4 p;
        p.x = (unsigned)f2bf(a.x) | ((unsigned)f2bf(a.y) << 16);
        p.y = (unsigned)f2bf(a.z) | ((unsigned)f2bf(a.w) << 16);
        p.z = (unsigned)f2bf(b.x) | ((unsigned)f2bf(b.y) << 16);
        p.w = (unsigned)f2bf(b.z) | ((unsigned)f2bf(b.w) << 16);
        ((uint4*)dst)[i] = p;
    }
}

// ---------------- router (blocks<1024) + fused W1 convert (blocks>=1024) ---
__global__ __launch_bounds__(256) void routerconv_kernel(
    const float* __restrict__ x, const float* __restrict__ Wr,
    int* __restrict__ counts, int* __restrict__ tlist,
    float* __restrict__ gates, ushort* __restrict__ xb,
    const float* __restrict__ csrc, ushort* __restrict__ cdst)
{
    if (blockIdx.x >= 1024) {
        convert_body(csrc, cdst, (blockIdx.x - 1024) * 256 + threadIdx.x, 2048 * 256);
        return;
    }
    const int lane = threadIdx.x & 63;
    const int wv   = threadIdx.x >> 6;
    const int t    = blockIdx.x * 4 + wv;
    const float* xr = x + (size_t)t * DDIM;
    float xv[12];
#pragma unroll
    for (int i = 0; i < 12; ++i) xv[i] = xr[lane + 64 * i];
#pragma unroll
    for (int i = 0; i < 12; ++i) xb[(size_t)t * DDIM + lane + 64 * i] = f2bf(xv[i]);

    float acc[EXP];
#pragma unroll
    for (int e = 0; e < EXP; ++e) {
        const float* wr = Wr + e * DDIM;
        float a = 0.f;
#pragma unroll
        for (int i = 0; i < 12; ++i) a += xv[i] * wr[lane + 64 * i];
        acc[e] = a;
    }
#pragma unroll
    for (int off = 32; off > 0; off >>= 1) {
#pragma unroll
        for (int e = 0; e < EXP; ++e) acc[e] += __shfl_xor(acc[e], off);
    }
    if (lane == 0) {
        // complexity bias is uniform over experts -> softmax/argmax invariant
        float m = acc[0]; int am = 0;
#pragma unroll
        for (int e = 1; e < EXP; ++e) if (acc[e] > m) { m = acc[e]; am = e; }
        float s = 0.f;
#pragma unroll
        for (int e = 0; e < EXP; ++e) s += expf(acc[e] - m);
        gates[t] = 1.0f / s;
        int pos = atomicAdd(&counts[am], 1);
        tlist[am * T_TOK + pos] = t;
    }
}

// ---------------- standalone convert (fallback path) -----------------------
__global__ __launch_bounds__(256) void convert_kernel(
    const float* __restrict__ src, ushort* __restrict__ dst)
{
    convert_body(src, dst, blockIdx.x * 256 + threadIdx.x, gridDim.x * 256);
}

// ---------------- grouped GEMM, 2-phase prefetch double-buffer -------------
// C[slot, n] = sum_k A[tl[slot], s*KLEN + k] * W[e, n0+n, s*KLEN + k]
// MODE 1: GELU -> H bf16 (z==EXP slice does fused W2 convert)
// MODE 2: unsafeAtomicAdd(Out, v*gate), split index s = z>>3
template <int BM, int BN, int BK, int NTOT, int KSTRIDE, int KLEN, int MODE>
__global__ __launch_bounds__(256, 3) void moe_gemm(
    const ushort* __restrict__ A, const ushort* __restrict__ W,
    ushort* __restrict__ H, float* __restrict__ Out,
    const int* __restrict__ counts, const int* __restrict__ tlist,
    const float* __restrict__ gates,
    const float* __restrict__ csrc, ushort* __restrict__ cdst)
{
    constexpr int ACH = BM * BK * 2 / 1024;   // A chunks (1 KB each)
    constexpr int NCH = (BM + BN) * BK * 2 / 1024;
    constexpr int CPW = NCH / 4;              // chunks per wave
    constexpr int RPC = 512 / BK;             // rows per chunk
    constexpr int LPR = BK / 8;               // lanes per row
    constexpr int HT  = (BM + BN) * BK * 2;   // bytes per LDS buffer
    constexpr int MR  = BM / 32, NR = BN / 32;
    constexpr int NT  = KLEN / BK;
    constexpr int KS  = BK / 32;

    if (MODE == 1 && blockIdx.z == EXP) {     // fused W2 convert slice
        convert_body(csrc, cdst,
                     (blockIdx.y * gridDim.x + blockIdx.x) * 256 + threadIdx.x,
                     gridDim.x * gridDim.y * 256);
        return;
    }
    const int e  = blockIdx.z & (EXP - 1);
    const int s  = (MODE == 2) ? (blockIdx.z >> 3) : 0;
    const int Ne = counts[e];
    const int m0 = blockIdx.y * BM;
    if (m0 >= Ne) return;
    const int n0 = blockIdx.x * BN;

    __shared__ ushort Sh[HT];                 // 2 buffers of HT/2... (HT bytes *2)/2
    __shared__ ushort Sh2[HT];
    char* Sb0 = (char*)Sh;
    char* Sb1 = (char*)Sh2;

    const int tid = threadIdx.x, lane = tid & 63, wv = tid >> 6;
    const int* tl = tlist + e * T_TOK;

    const ushort* bp[CPW];
#pragma unroll
    for (int i = 0; i < CPW; ++i) {
        const int c = wv * CPW + i;
        if (c < ACH) {
            int slot = m0 + c * RPC + lane / LPR;
            if (slot > Ne - 1) slot = Ne - 1;
            bp[i] = A + (size_t)tl[slot] * KSTRIDE + s * KLEN + (lane % LPR) * 8;
        } else {
            const int r = (c - ACH) * RPC + lane / LPR;
            bp[i] = W + ((size_t)e * NTOT + n0 + r) * KSTRIDE + s * KLEN + (lane % LPR) * 8;
        }
    }

    f32x4 acc[MR][NR];
#pragma unroll
    for (int m = 0; m < MR; ++m)
#pragma unroll
        for (int n = 0; n < NR; ++n) acc[m][n] = (f32x4)0.f;

    const int wrow = (wv >> 1) * (BM / 2);
    const int wcol = (wv & 1) * (BN / 2);

    // prologue: stage tile 0 into buffer 0
#pragma unroll
    for (int i = 0; i < CPW; ++i)
        gl_lds16(bp[i], Sb0 + (wv * CPW + i) * 1024);

    for (int t = 0; t < NT; ++t) {
        char* curB = (t & 1) ? Sb1 : Sb0;
        char* nxtB = (t & 1) ? Sb0 : Sb1;
        __syncthreads();                      // implicit vmcnt(0): cur buffer ready
        if (t + 1 < NT) {
#pragma unroll
            for (int i = 0; i < CPW; ++i)
                gl_lds16(bp[i] + (t + 1) * BK, nxtB + (wv * CPW + i) * 1024);
        }
#pragma unroll
        for (int ks = 0; ks < KS; ++ks) {
            const int kb = ks * 64 + (lane >> 4) * 16;
            bf16x8 af[MR], bfr[NR];
#pragma unroll
            for (int m = 0; m < MR; ++m) {
                const int r = wrow + m * 16 + (lane & 15);
                af[m] = *(const bf16x8*)(curB + r * (2 * BK) + kb);
            }
#pragma unroll
            for (int n = 0; n < NR; ++n) {
                const int r = wcol + n * 16 + (lane & 15);
                bfr[n] = *(const bf16x8*)(curB + BM * (2 * BK) + r * (2 * BK) + kb);
            }
#pragma unroll
            for (int m = 0; m < MR; ++m)
#pragma unroll
                for (int n = 0; n < NR; ++n)
                    acc[m][n] = __builtin_amdgcn_mfma_f32_16x16x32_bf16(
                        af[m], bfr[n], acc[m][n], 0, 0, 0);
        }
    }

    // epilogue: C frag row=(lane>>4)*4+j, col=lane&15  [m89 layout]
    const int lr4 = (lane >> 4) * 4, lc = lane & 15;
#pragma unroll
    for (int m = 0; m < MR; ++m) {
        const int rbase = wrow + m * 16 + lr4;
#pragma unroll
        for (int j = 0; j < 4; ++j) {
            const int slot = m0 + rbase + j;
            if (slot >= Ne) continue;
            const int t = tl[slot];
            const float g = (MODE == 2) ? gates[t] : 0.f;
#pragma unroll
            for (int n = 0; n < NR; ++n) {
                float v = acc[m][n][j];
                const int c = n0 + wcol + n * 16 + lc;
                if (MODE == 1) {
                    float gv = 0.5f * v * (1.0f + erff(v * 0.70710678118654752f));
                    H[(size_t)t * NTOT + c] = f2bf(gv);
                } else {
                    unsafeAtomicAdd(&Out[(size_t)t * NTOT + c], v * g);
                }
            }
        }
    }
}

// ---------------- finalize: lb_loss, counts, avg gate, active --------------
__global__ __launch_bounds__(256) void finalize_kernel(
    const float* __restrict__ gates, const int* __restrict__ counts,
    float* __restrict__ tail)
{
    __shared__ float red[256];
    float s = 0.f;
    for (int i = threadIdx.x; i < T_TOK; i += 256) s += gates[i];
    red[threadIdx.x] = s;
    __syncthreads();
    for (int off = 128; off > 0; off >>= 1) {
        if (threadIdx.x < off) red[threadIdx.x] += red[threadIdx.x + off];
        __syncthreads();
    }
    if (threadIdx.x == 0) {
        float lb = 0.f; int active = 0;
#pragma unroll
        for (int e = 0; e < EXP; ++e) {
            float c = (float)counts[e];
            float d = c - 512.0f;
            lb += d * d;
            active += (counts[e] > 0) ? 1 : 0;
        }
        tail[0] = lb * (0.01f / 8.0f);
#pragma unroll
        for (int e = 0; e < EXP; ++e) tail[1 + e] = (float)counts[e];
        tail[9]  = red[0] / (float)T_TOK;
        tail[10] = (float)active;
    }
}

// ---------------- launch ---------------------------------------------------
extern "C" void kernel_launch(void* const* d_in, const int* in_sizes, int n_in,
                              void* d_out, int out_size, void* d_ws, size_t ws_size,
                              hipStream_t stream)
{
    const float* x  = (const float*)d_in[0];
    const float* Wr = (const float*)d_in[2];
    const float* W1 = (const float*)d_in[5];
    const float* W2 = (const float*)d_in[6];
    float* out = (float*)d_out;

    char* ws = (char*)d_ws;
    int*    counts = (int*)ws;                       // 256 B
    int*    tlist  = (int*)(ws + 256);               // 128 KiB
    float*  gates  = (float*)(ws + 131328);          // 16 KiB
    ushort* xb     = (ushort*)(ws + 147712);         // 6.29 MB
    ushort* h      = (ushort*)(ws + 6439168);        // 25.2 MB
    ushort* w1b    = (ushort*)(ws + 31604992);       // 37.75 MB
    const size_t OFF_W2B = 69353728ull;
    const bool fuse = ws_size >= OFF_W2B + 37748736ull;
    ushort* w2b = fuse ? (ushort*)(ws + OFF_W2B) : w1b;

    hipMemsetAsync(counts, 0, 256, stream);
    routerconv_kernel<<<dim3(3072), dim3(256), 0, stream>>>(
        x, Wr, counts, tlist, gates, xb, W1, w1b);

    // GEMM1: BM=128 BN=128 BK=32, KLEN=768, 24 K-steps, LDS 32KB -> 3 blk/CU
    if (fuse) {
        moe_gemm<128, 128, 32, FDIM, DDIM, DDIM, 1>
            <<<dim3(FDIM / 128, T_TOK / 128, EXP + 1), dim3(256), 0, stream>>>(
            xb, w1b, h, nullptr, counts, tlist, gates, W2, w2b);
    } else {
        moe_gemm<128, 128, 32, FDIM, DDIM, DDIM, 1>
            <<<dim3(FDIM / 128, T_TOK / 128, EXP), dim3(256), 0, stream>>>(
            xb, w1b, h, nullptr, counts, tlist, gates, nullptr, nullptr);
        convert_kernel<<<dim3(2048), dim3(256), 0, stream>>>(W2, w2b);
    }

    // GEMM2: BM=128 BN=64 BK=64, split-K=2 (KLEN=1536), atomic f32 epilogue
    hipMemsetAsync(out, 0, (size_t)T_TOK * DDIM * sizeof(float), stream);
    moe_gemm<128, 64, 64, DDIM, FDIM, FDIM / 2, 2>
        <<<dim3(DDIM / 64, T_TOK / 128, EXP * 2), dim3(256), 0, stream>>>(
        h, w2b, nullptr, out, counts, tlist, gates, nullptr, nullptr);

    finalize_kernel<<<dim3(1), dim3(256), 0, stream>>>(gates, counts, out + (size_t)T_TOK * DDIM);
}

// Round 4
// 353.887 us; speedup vs baseline: 1.0927x; 1.0927x over previous
//
#include <hip/hip_runtime.h>
#include <math.h>

// Problem constants (B=2,S=2048,D=768,E=8,F=3072)
#define T_TOK 4096
#define DDIM  768
#define EXP   8
#define FDIM  3072
#define W8CNT ((EXP * FDIM * DDIM) / 8)   // 2359296 8-float units per weight tensor

typedef __bf16 bf16x8 __attribute__((ext_vector_type(8)));
typedef float  f32x4  __attribute__((ext_vector_type(4)));

__device__ __forceinline__ ushort f2bf(float f) {
    union { float f; unsigned u; } v; v.f = f;
    unsigned r = v.u + 0x7fffu + ((v.u >> 16) & 1u);   // RNE
    return (ushort)(r >> 16);
}

// async global->LDS, 16B per lane; LDS base wave-uniform (HW adds lane*16)
__device__ __forceinline__ void gl_lds16(const void* g, void* l) {
    __builtin_amdgcn_global_load_lds(
        (__attribute__((address_space(1))) void*)(g),
        (__attribute__((address_space(3))) void*)(l), 16, 0, 0);
}

__device__ __forceinline__ void convert_body(const float* __restrict__ src,
                                             ushort* __restrict__ dst,
                                             int idx0, int stride) {
    for (int i = idx0; i < W8CNT; i += stride) {
        const float4* s = (const float4*)(src + (size_t)i * 8);
        float4 a = s[0], b = s[1];
        uint4 p;
        p.x = (unsigned)f2bf(a.x) | ((unsigned)f2bf(a.y) << 16);
        p.y = (unsigned)f2bf(a.z) | ((unsigned)f2bf(a.w) << 16);
        p.z = (unsigned)f2bf(b.x) | ((unsigned)f2bf(b.y) << 16);
        p.w = (unsigned)f2bf(b.z) | ((unsigned)f2bf(b.w) << 16);
        ((uint4*)dst)[i] = p;
    }
}

// ---------------- router (blocks<1024) + fused W1 convert (blocks>=1024) ---
__global__ __launch_bounds__(256) void routerconv_kernel(
    const float* __restrict__ x, const float* __restrict__ Wr,
    int* __restrict__ counts, int* __restrict__ tlist,
    float* __restrict__ gates, ushort* __restrict__ xb,
    const float* __restrict__ csrc, ushort* __restrict__ cdst)
{
    if (blockIdx.x >= 1024) {
        convert_body(csrc, cdst, (blockIdx.x - 1024) * 256 + threadIdx.x, 2048 * 256);
        return;
    }
    const int lane = threadIdx.x & 63;
    const int wv   = threadIdx.x >> 6;
    const int t    = blockIdx.x * 4 + wv;
    const float* xr = x + (size_t)t * DDIM;
    float xv[12];
#pragma unroll
    for (int i = 0; i < 12; ++i) xv[i] = xr[lane + 64 * i];
#pragma unroll
    for (int i = 0; i < 12; ++i) xb[(size_t)t * DDIM + lane + 64 * i] = f2bf(xv[i]);

    float acc[EXP];
#pragma unroll
    for (int e = 0; e < EXP; ++e) {
        const float* wr = Wr + e * DDIM;
        float a = 0.f;
#pragma unroll
        for (int i = 0; i < 12; ++i) a += xv[i] * wr[lane + 64 * i];
        acc[e] = a;
    }
#pragma unroll
    for (int off = 32; off > 0; off >>= 1) {
#pragma unroll
        for (int e = 0; e < EXP; ++e) acc[e] += __shfl_xor(acc[e], off);
    }
    if (lane == 0) {
        // complexity bias is uniform over experts -> softmax/argmax invariant
        float m = acc[0]; int am = 0;
#pragma unroll
        for (int e = 1; e < EXP; ++e) if (acc[e] > m) { m = acc[e]; am = e; }
        float s = 0.f;
#pragma unroll
        for (int e = 0; e < EXP; ++e) s += expf(acc[e] - m);
        gates[t] = 1.0f / s;
        int pos = atomicAdd(&counts[am], 1);
        tlist[am * T_TOK + pos] = t;
    }
}

// ---------------- standalone convert (fallback path) -----------------------
__global__ __launch_bounds__(256) void convert_kernel(
    const float* __restrict__ src, ushort* __restrict__ dst)
{
    convert_body(src, dst, blockIdx.x * 256 + threadIdx.x, gridDim.x * 256);
}

// ---------------- grouped GEMM, 2-phase prefetch double-buffer -------------
// C[slot, n] = sum_k A[tl[slot], s*KLEN + k] * W[e, n0+n, s*KLEN + k]
// MODE 1: GELU -> H bf16 (z==EXP slice does fused W2 convert)
// MODE 2: unsafeAtomicAdd(Out, v*gate), split index s = z>>3
template <int BM, int BN, int BK, int NTOT, int KSTRIDE, int KLEN, int MODE>
__global__ __launch_bounds__(256, 3) void moe_gemm(
    const ushort* __restrict__ A, const ushort* __restrict__ W,
    ushort* __restrict__ H, float* __restrict__ Out,
    const int* __restrict__ counts, const int* __restrict__ tlist,
    const float* __restrict__ gates,
    const float* __restrict__ csrc, ushort* __restrict__ cdst)
{
    constexpr int ACH = BM * BK * 2 / 1024;   // A chunks (1 KB each)
    constexpr int NCH = (BM + BN) * BK * 2 / 1024;
    constexpr int CPW = NCH / 4;              // chunks per wave
    constexpr int RPC = 512 / BK;             // rows per chunk
    constexpr int LPR = BK / 8;               // lanes per row
    constexpr int HT  = (BM + BN) * BK * 2;   // BYTES per LDS buffer
    constexpr int MR  = BM / 32, NR = BN / 32;
    constexpr int NT  = KLEN / BK;
    constexpr int KS  = BK / 32;

    if (MODE == 1 && blockIdx.z == EXP) {     // fused W2 convert slice
        convert_body(csrc, cdst,
                     (blockIdx.y * gridDim.x + blockIdx.x) * 256 + threadIdx.x,
                     gridDim.x * gridDim.y * 256);
        return;
    }
    const int e  = blockIdx.z & (EXP - 1);
    const int s  = (MODE == 2) ? (blockIdx.z >> 3) : 0;
    const int Ne = counts[e];
    const int m0 = blockIdx.y * BM;
    if (m0 >= Ne) return;
    const int n0 = blockIdx.x * BN;

    // double buffer: HT bytes each (round-3 bug: ushort[HT] was 2x too big)
    __shared__ __align__(16) char S[2 * HT];
    char* Sb0 = S;
    char* Sb1 = S + HT;

    const int tid = threadIdx.x, lane = tid & 63, wv = tid >> 6;
    const int* tl = tlist + e * T_TOK;

    const ushort* bp[CPW];
#pragma unroll
    for (int i = 0; i < CPW; ++i) {
        const int c = wv * CPW + i;
        if (c < ACH) {
            int slot = m0 + c * RPC + lane / LPR;
            if (slot > Ne - 1) slot = Ne - 1;
            bp[i] = A + (size_t)tl[slot] * KSTRIDE + s * KLEN + (lane % LPR) * 8;
        } else {
            const int r = (c - ACH) * RPC + lane / LPR;
            bp[i] = W + ((size_t)e * NTOT + n0 + r) * KSTRIDE + s * KLEN + (lane % LPR) * 8;
        }
    }

    f32x4 acc[MR][NR];
#pragma unroll
    for (int m = 0; m < MR; ++m)
#pragma unroll
        for (int n = 0; n < NR; ++n) acc[m][n] = (f32x4)0.f;

    const int wrow = (wv >> 1) * (BM / 2);
    const int wcol = (wv & 1) * (BN / 2);

    // prologue: stage tile 0 into buffer 0
#pragma unroll
    for (int i = 0; i < CPW; ++i)
        gl_lds16(bp[i], Sb0 + (wv * CPW + i) * 1024);

    for (int t = 0; t < NT; ++t) {
        char* curB = (t & 1) ? Sb1 : Sb0;
        char* nxtB = (t & 1) ? Sb0 : Sb1;
        __syncthreads();                      // implicit vmcnt(0): cur buffer ready
        if (t + 1 < NT) {
#pragma unroll
            for (int i = 0; i < CPW; ++i)
                gl_lds16(bp[i] + (t + 1) * BK, nxtB + (wv * CPW + i) * 1024);
        }
#pragma unroll
        for (int ks = 0; ks < KS; ++ks) {
            const int kb = ks * 64 + (lane >> 4) * 16;
            bf16x8 af[MR], bfr[NR];
#pragma unroll
            for (int m = 0; m < MR; ++m) {
                const int r = wrow + m * 16 + (lane & 15);
                af[m] = *(const bf16x8*)(curB + r * (2 * BK) + kb);
            }
#pragma unroll
            for (int n = 0; n < NR; ++n) {
                const int r = wcol + n * 16 + (lane & 15);
                bfr[n] = *(const bf16x8*)(curB + BM * (2 * BK) + r * (2 * BK) + kb);
            }
#pragma unroll
            for (int m = 0; m < MR; ++m)
#pragma unroll
                for (int n = 0; n < NR; ++n)
                    acc[m][n] = __builtin_amdgcn_mfma_f32_16x16x32_bf16(
                        af[m], bfr[n], acc[m][n], 0, 0, 0);
        }
    }

    // epilogue: C frag row=(lane>>4)*4+j, col=lane&15  [m89 layout]
    const int lr4 = (lane >> 4) * 4, lc = lane & 15;
#pragma unroll
    for (int m = 0; m < MR; ++m) {
        const int rbase = wrow + m * 16 + lr4;
#pragma unroll
        for (int j = 0; j < 4; ++j) {
            const int slot = m0 + rbase + j;
            if (slot >= Ne) continue;
            const int t = tl[slot];
            const float g = (MODE == 2) ? gates[t] : 0.f;
#pragma unroll
            for (int n = 0; n < NR; ++n) {
                float v = acc[m][n][j];
                const int c = n0 + wcol + n * 16 + lc;
                if (MODE == 1) {
                    float gv = 0.5f * v * (1.0f + erff(v * 0.70710678118654752f));
                    H[(size_t)t * NTOT + c] = f2bf(gv);
                } else {
                    unsafeAtomicAdd(&Out[(size_t)t * NTOT + c], v * g);
                }
            }
        }
    }
}

// ---------------- finalize: lb_loss, counts, avg gate, active --------------
__global__ __launch_bounds__(256) void finalize_kernel(
    const float* __restrict__ gates, const int* __restrict__ counts,
    float* __restrict__ tail)
{
    __shared__ float red[256];
    float s = 0.f;
    for (int i = threadIdx.x; i < T_TOK; i += 256) s += gates[i];
    red[threadIdx.x] = s;
    __syncthreads();
    for (int off = 128; off > 0; off >>= 1) {
        if (threadIdx.x < off) red[threadIdx.x] += red[threadIdx.x + off];
        __syncthreads();
    }
    if (threadIdx.x == 0) {
        float lb = 0.f; int active = 0;
#pragma unroll
        for (int e = 0; e < EXP; ++e) {
            float c = (float)counts[e];
            float d = c - 512.0f;
            lb += d * d;
            active += (counts[e] > 0) ? 1 : 0;
        }
        tail[0] = lb * (0.01f / 8.0f);
#pragma unroll
        for (int e = 0; e < EXP; ++e) tail[1 + e] = (float)counts[e];
        tail[9]  = red[0] / (float)T_TOK;
        tail[10] = (float)active;
    }
}

// ---------------- launch ---------------------------------------------------
extern "C" void kernel_launch(void* const* d_in, const int* in_sizes, int n_in,
                              void* d_out, int out_size, void* d_ws, size_t ws_size,
                              hipStream_t stream)
{
    const float* x  = (const float*)d_in[0];
    const float* Wr = (const float*)d_in[2];
    const float* W1 = (const float*)d_in[5];
    const float* W2 = (const float*)d_in[6];
    float* out = (float*)d_out;

    char* ws = (char*)d_ws;
    int*    counts = (int*)ws;                       // 256 B
    int*    tlist  = (int*)(ws + 256);               // 128 KiB
    float*  gates  = (float*)(ws + 131328);          // 16 KiB
    ushort* xb     = (ushort*)(ws + 147712);         // 6.29 MB
    ushort* h      = (ushort*)(ws + 6439168);        // 25.2 MB
    ushort* w1b    = (ushort*)(ws + 31604992);       // 37.75 MB
    const size_t OFF_W2B = 69353728ull;
    const bool fuse = ws_size >= OFF_W2B + 37748736ull;
    ushort* w2b = fuse ? (ushort*)(ws + OFF_W2B) : w1b;

    hipMemsetAsync(counts, 0, 256, stream);
    routerconv_kernel<<<dim3(3072), dim3(256), 0, stream>>>(
        x, Wr, counts, tlist, gates, xb, W1, w1b);

    // GEMM1: BM=128 BN=128 BK=32, 24 K-steps, LDS 32KB -> 3 blk/CU
    if (fuse) {
        moe_gemm<128, 128, 32, FDIM, DDIM, DDIM, 1>
            <<<dim3(FDIM / 128, T_TOK / 128, EXP + 1), dim3(256), 0, stream>>>(
            xb, w1b, h, nullptr, counts, tlist, gates, W2, w2b);
    } else {
        moe_gemm<128, 128, 32, FDIM, DDIM, DDIM, 1>
            <<<dim3(FDIM / 128, T_TOK / 128, EXP), dim3(256), 0, stream>>>(
            xb, w1b, h, nullptr, counts, tlist, gates, nullptr, nullptr);
        convert_kernel<<<dim3(2048), dim3(256), 0, stream>>>(W2, w2b);
    }

    // GEMM2: BM=128 BN=64 BK=64, split-K=2, LDS 48KB -> 3 blk/CU
    hipMemsetAsync(out, 0, (size_t)T_TOK * DDIM * sizeof(float), stream);
    moe_gemm<128, 64, 64, DDIM, FDIM, FDIM / 2, 2>
        <<<dim3(DDIM / 64, T_TOK / 128, EXP * 2), dim3(256), 0, stream>>>(
        h, w2b, nullptr, out, counts, tlist, gates, nullptr, nullptr);

    finalize_kernel<<<dim3(1), dim3(256), 0, stream>>>(gates, counts, out + (size_t)T_TOK * DDIM);
}

// Round 5
// 352.240 us; speedup vs baseline: 1.0978x; 1.0047x over previous
//
#include <hip/hip_runtime.h>
#include <math.h>

// Problem constants (B=2,S=2048,D=768,E=8,F=3072)
#define T_TOK 4096
#define DDIM  768
#define EXP   8
#define FDIM  3072
#define W8CNT ((EXP * FDIM * DDIM) / 8)   // 2359296 8-float units per weight tensor

typedef __bf16 bf16x8 __attribute__((ext_vector_type(8)));
typedef float  f32x4  __attribute__((ext_vector_type(4)));

__device__ __forceinline__ ushort f2bf(float f) {
    union { float f; unsigned u; } v; v.f = f;
    unsigned r = v.u + 0x7fffu + ((v.u >> 16) & 1u);   // RNE
    return (ushort)(r >> 16);
}

// async global->LDS, 16B per lane; LDS base wave-uniform (HW adds lane*16)
__device__ __forceinline__ void gl_lds16(const void* g, void* l) {
    __builtin_amdgcn_global_load_lds(
        (__attribute__((address_space(1))) void*)(g),
        (__attribute__((address_space(3))) void*)(l), 16, 0, 0);
}

// counted vmem wait (T4): never drain to 0 in the main loop
template <int N> __device__ __forceinline__ void vm_wait() {
    if constexpr (N == 4)      asm volatile("s_waitcnt vmcnt(4)" ::: "memory");
    else if constexpr (N == 6) asm volatile("s_waitcnt vmcnt(6)" ::: "memory");
    else                       asm volatile("s_waitcnt vmcnt(0)" ::: "memory");
}
__device__ __forceinline__ void sbar() {
    __builtin_amdgcn_sched_barrier(0);
    __builtin_amdgcn_s_barrier();
    __builtin_amdgcn_sched_barrier(0);
}

__device__ __forceinline__ void convert_body(const float* __restrict__ src,
                                             ushort* __restrict__ dst,
                                             int idx0, int stride) {
    for (int i = idx0; i < W8CNT; i += stride) {
        const float4* s = (const float4*)(src + (size_t)i * 8);
        float4 a = s[0], b = s[1];
        uint4 p;
        p.x = (unsigned)f2bf(a.x) | ((unsigned)f2bf(a.y) << 16);
        p.y = (unsigned)f2bf(a.z) | ((unsigned)f2bf(a.w) << 16);
        p.z = (unsigned)f2bf(b.x) | ((unsigned)f2bf(b.y) << 16);
        p.w = (unsigned)f2bf(b.z) | ((unsigned)f2bf(b.w) << 16);
        ((uint4*)dst)[i] = p;
    }
}

// ---------------- router (blocks<1024) + fused W1 convert (blocks>=1024) ---
__global__ __launch_bounds__(256) void routerconv_kernel(
    const float* __restrict__ x, const float* __restrict__ Wr,
    int* __restrict__ counts, int* __restrict__ tlist,
    float* __restrict__ gates, ushort* __restrict__ xb,
    const float* __restrict__ csrc, ushort* __restrict__ cdst)
{
    if (blockIdx.x >= 1024) {
        convert_body(csrc, cdst, (blockIdx.x - 1024) * 256 + threadIdx.x, 2048 * 256);
        return;
    }
    const int lane = threadIdx.x & 63;
    const int wv   = threadIdx.x >> 6;
    const int t    = blockIdx.x * 4 + wv;
    const float4* xr4 = (const float4*)(x + (size_t)t * DDIM);
    float4 xv[3];
#pragma unroll
    for (int j = 0; j < 3; ++j) xv[j] = xr4[lane + 64 * j];
    uint2* xbw = (uint2*)(xb + (size_t)t * DDIM);
#pragma unroll
    for (int j = 0; j < 3; ++j) {
        uint2 p;
        p.x = (unsigned)f2bf(xv[j].x) | ((unsigned)f2bf(xv[j].y) << 16);
        p.y = (unsigned)f2bf(xv[j].z) | ((unsigned)f2bf(xv[j].w) << 16);
        xbw[lane + 64 * j] = p;
    }
    float acc[EXP];
#pragma unroll
    for (int e = 0; e < EXP; ++e) {
        const float4* wr4 = (const float4*)(Wr + e * DDIM);
        float a = 0.f;
#pragma unroll
        for (int j = 0; j < 3; ++j) {
            float4 w = wr4[lane + 64 * j];
            a += xv[j].x * w.x + xv[j].y * w.y + xv[j].z * w.z + xv[j].w * w.w;
        }
        acc[e] = a;
    }
#pragma unroll
    for (int off = 32; off > 0; off >>= 1) {
#pragma unroll
        for (int e = 0; e < EXP; ++e) acc[e] += __shfl_xor(acc[e], off);
    }
    if (lane == 0) {
        // complexity bias is uniform over experts -> softmax/argmax invariant
        float m = acc[0]; int am = 0;
#pragma unroll
        for (int e = 1; e < EXP; ++e) if (acc[e] > m) { m = acc[e]; am = e; }
        float s = 0.f;
#pragma unroll
        for (int e = 0; e < EXP; ++e) s += expf(acc[e] - m);
        gates[t] = 1.0f / s;
        int pos = atomicAdd(&counts[am], 1);
        tlist[am * T_TOK + pos] = t;
    }
}

// ---------------- standalone convert (fallback path) -----------------------
__global__ __launch_bounds__(256) void convert_kernel(
    const float* __restrict__ src, ushort* __restrict__ dst)
{
    convert_body(src, dst, blockIdx.x * 256 + threadIdx.x, gridDim.x * 256);
}

// ---------------- grouped GEMM: counted-vmcnt dbuf + both-sides swizzle ----
// C[slot, n] = sum_k A[tl[slot], s*KLEN + k] * W[e, n0+n, s*KLEN + k]
// MODE 1: GELU -> H bf16 (z==EXP slice does fused W2 convert)
// MODE 2: unsafeAtomicAdd(Out, v*gate), split index s = z>>3
template <int BM, int BN, int BK, int NTOT, int KSTRIDE, int KLEN, int MODE>
__global__ __launch_bounds__(256, 4) void moe_gemm(
    const ushort* __restrict__ A, const ushort* __restrict__ W,
    ushort* __restrict__ H, float* __restrict__ Out,
    const int* __restrict__ counts, const int* __restrict__ tlist,
    const float* __restrict__ gates,
    const float* __restrict__ csrc, ushort* __restrict__ cdst)
{
    constexpr int ACH = BM * BK * 2 / 1024;   // A chunks (1 KB each)
    constexpr int NCH = (BM + BN) * BK * 2 / 1024;
    constexpr int CPW = NCH / 4;              // chunks per wave per tile
    constexpr int RPC = 512 / BK;             // rows per chunk
    constexpr int LPR = BK / 8;               // lanes per row (= 16B slots per row)
    constexpr int HT  = (BM + BN) * BK * 2;   // bytes per LDS buffer
    constexpr int MR  = BM / 32, NR = BN / 32;
    constexpr int NT  = KLEN / BK;
    constexpr int KS  = BK / 32;
    constexpr int SWM = LPR - 1;              // swizzle mask over 16B slots

    if (MODE == 1 && blockIdx.z == EXP) {     // fused W2 convert slice
        convert_body(csrc, cdst,
                     (blockIdx.y * gridDim.x + blockIdx.x) * 256 + threadIdx.x,
                     gridDim.x * gridDim.y * 256);
        return;
    }
    const int e  = blockIdx.z & (EXP - 1);
    const int s  = (MODE == 2) ? (blockIdx.z >> 3) : 0;
    const int Ne = counts[e];
    const int m0 = blockIdx.y * BM;
    if (m0 >= Ne) return;
    const int n0 = blockIdx.x * BN;

    __shared__ __align__(16) char S[2 * HT];
    char* Sb0 = S;
    char* Sb1 = S + HT;

    const int tid = threadIdx.x, lane = tid & 63, wv = tid >> 6;
    const int* tl = tlist + e * T_TOK;

    // per-lane global pointers, source pre-swizzled: slot' = slot ^ (row & SWM)
    // (gl_lds writes LDS linearly -> swizzle must live in the source addr, #21)
    const ushort* bp[CPW];
#pragma unroll
    for (int i = 0; i < CPW; ++i) {
        const int c = wv * CPW + i;
        const int rl = lane / LPR;            // row within chunk
        const int sl = (lane % LPR) ^ (rl & SWM);
        if (c < ACH) {
            int slot = m0 + c * RPC + rl;
            if (slot > Ne - 1) slot = Ne - 1;
            bp[i] = A + (size_t)tl[slot] * KSTRIDE + s * KLEN + sl * 8;
        } else {
            const int r = (c - ACH) * RPC + rl;
            bp[i] = W + ((size_t)e * NTOT + n0 + r) * KSTRIDE + s * KLEN + sl * 8;
        }
    }

    f32x4 acc[MR][NR];
#pragma unroll
    for (int m = 0; m < MR; ++m)
#pragma unroll
        for (int n = 0; n < NR; ++n) acc[m][n] = (f32x4)0.f;

    const int wrow = (wv >> 1) * (BM / 2);
    const int wcol = (wv & 1) * (BN / 2);

#define STAGE(T, BUF)                                                   \
    {                                                                   \
        _Pragma("unroll")                                               \
        for (int i = 0; i < CPW; ++i)                                   \
            gl_lds16(bp[i] + (T) * BK, (BUF) + (wv * CPW + i) * 1024);  \
    }

    // prologue: 2 tiles in flight
    STAGE(0, Sb0);
    STAGE(1, Sb1);

    for (int t = 0; t < NT; ++t) {
        char* curB = (t & 1) ? Sb1 : Sb0;
        vm_wait<CPW>();                       // tile t landed; tile t+1 stays in flight
        sbar();
#pragma unroll
        for (int ks = 0; ks < KS; ++ks) {
            const int kb = ks * 64 + (lane >> 4) * 16;
            bf16x8 af[MR], bfr[NR];
#pragma unroll
            for (int m = 0; m < MR; ++m) {
                const int r = wrow + m * 16 + (lane & 15);
                const int b = (r * (2 * BK) + kb) ^ ((r & SWM) << 4);
                af[m] = *(const bf16x8*)(curB + b);
            }
#pragma unroll
            for (int n = 0; n < NR; ++n) {
                const int r = wcol + n * 16 + (lane & 15);
                const int b = (r * (2 * BK) + kb) ^ ((r & SWM) << 4);
                bfr[n] = *(const bf16x8*)(curB + BM * (2 * BK) + b);
            }
#pragma unroll
            for (int m = 0; m < MR; ++m)
#pragma unroll
                for (int n = 0; n < NR; ++n)
                    acc[m][n] = __builtin_amdgcn_mfma_f32_16x16x32_bf16(
                        af[m], bfr[n], acc[m][n], 0, 0, 0);
        }
        sbar();                               // all waves done reading curB
        if (t + 2 < NT) STAGE(t + 2, curB);
    }
#undef STAGE

    // epilogue: C frag row=(lane>>4)*4+j, col=lane&15  [m89 layout]
    const int lr4 = (lane >> 4) * 4, lc = lane & 15;
#pragma unroll
    for (int m = 0; m < MR; ++m) {
        const int rbase = wrow + m * 16 + lr4;
#pragma unroll
        for (int j = 0; j < 4; ++j) {
            const int slot = m0 + rbase + j;
            if (slot >= Ne) continue;
            const int t = tl[slot];
            const float g = (MODE == 2) ? gates[t] : 0.f;
#pragma unroll
            for (int n = 0; n < NR; ++n) {
                float v = acc[m][n][j];
                const int c = n0 + wcol + n * 16 + lc;
                if (MODE == 1) {
                    float gv = 0.5f * v * (1.0f + erff(v * 0.70710678118654752f));
                    H[(size_t)t * NTOT + c] = f2bf(gv);
                } else {
                    unsafeAtomicAdd(&Out[(size_t)t * NTOT + c], v * g);
                }
            }
        }
    }
}

// ---------------- finalize: lb_loss, counts, avg gate, active --------------
__global__ __launch_bounds__(256) void finalize_kernel(
    const float* __restrict__ gates, const int* __restrict__ counts,
    float* __restrict__ tail)
{
    __shared__ float red[256];
    float s = 0.f;
    for (int i = threadIdx.x; i < T_TOK; i += 256) s += gates[i];
    red[threadIdx.x] = s;
    __syncthreads();
    for (int off = 128; off > 0; off >>= 1) {
        if (threadIdx.x < off) red[threadIdx.x] += red[threadIdx.x + off];
        __syncthreads();
    }
    if (threadIdx.x == 0) {
        float lb = 0.f; int active = 0;
#pragma unroll
        for (int e = 0; e < EXP; ++e) {
            float c = (float)counts[e];
            float d = c - 512.0f;
            lb += d * d;
            active += (counts[e] > 0) ? 1 : 0;
        }
        tail[0] = lb * (0.01f / 8.0f);
#pragma unroll
        for (int e = 0; e < EXP; ++e) tail[1 + e] = (float)counts[e];
        tail[9]  = red[0] / (float)T_TOK;
        tail[10] = (float)active;
    }
}

// ---------------- launch ---------------------------------------------------
extern "C" void kernel_launch(void* const* d_in, const int* in_sizes, int n_in,
                              void* d_out, int out_size, void* d_ws, size_t ws_size,
                              hipStream_t stream)
{
    const float* x  = (const float*)d_in[0];
    const float* Wr = (const float*)d_in[2];
    const float* W1 = (const float*)d_in[5];
    const float* W2 = (const float*)d_in[6];
    float* out = (float*)d_out;

    char* ws = (char*)d_ws;
    int*    counts = (int*)ws;                       // 256 B
    int*    tlist  = (int*)(ws + 256);               // 128 KiB
    float*  gates  = (float*)(ws + 131328);          // 16 KiB
    ushort* xb     = (ushort*)(ws + 147712);         // 6.29 MB
    ushort* h      = (ushort*)(ws + 6439168);        // 25.2 MB
    ushort* w1b    = (ushort*)(ws + 31604992);       // 37.75 MB
    const size_t OFF_W2B = 69353728ull;
    const bool fuse = ws_size >= OFF_W2B + 37748736ull;
    ushort* w2b = fuse ? (ushort*)(ws + OFF_W2B) : w1b;

    hipMemsetAsync(counts, 0, 256, stream);
    routerconv_kernel<<<dim3(3072), dim3(256), 0, stream>>>(
        x, Wr, counts, tlist, gates, xb, W1, w1b);

    // GEMM1: BM=128 BN=128 BK=32 (CPW=4), 24 K-steps, LDS 32KB
    if (fuse) {
        moe_gemm<128, 128, 32, FDIM, DDIM, DDIM, 1>
            <<<dim3(FDIM / 128, T_TOK / 128, EXP + 1), dim3(256), 0, stream>>>(
            xb, w1b, h, nullptr, counts, tlist, gates, W2, w2b);
    } else {
        moe_gemm<128, 128, 32, FDIM, DDIM, DDIM, 1>
            <<<dim3(FDIM / 128, T_TOK / 128, EXP), dim3(256), 0, stream>>>(
            xb, w1b, h, nullptr, counts, tlist, gates, nullptr, nullptr);
        convert_kernel<<<dim3(2048), dim3(256), 0, stream>>>(W2, w2b);
    }

    // GEMM2: BM=128 BN=64 BK=64 (CPW=6), split-K=2, LDS 48KB
    hipMemsetAsync(out, 0, (size_t)T_TOK * DDIM * sizeof(float), stream);
    moe_gemm<128, 64, 64, DDIM, FDIM, FDIM / 2, 2>
        <<<dim3(DDIM / 64, T_TOK / 128, EXP * 2), dim3(256), 0, stream>>>(
        h, w2b, nullptr, out, counts, tlist, gates, nullptr, nullptr);

    finalize_kernel<<<dim3(1), dim3(256), 0, stream>>>(gates, counts, out + (size_t)T_TOK * DDIM);
}